// Round 8
// baseline (135.376 us; speedup 1.0000x reference)
//
#include <hip/hip_runtime.h>
#include <hip/hip_bf16.h>
#include <cstdint>
#include <cstddef>

typedef __attribute__((ext_vector_type(8))) short short8;
typedef __attribute__((ext_vector_type(4))) float f32x4;

static constexpr int M_TOT = 31744;
static constexpr int N_TOT = 1152;
static constexpr int K_TOT = 768;
static constexpr long A_ELEMS = (long)M_TOT * K_TOT;   // 24379392
static constexpr long W_ELEMS = (long)N_TOT * K_TOT;   // 884736
static constexpr int CYC_ROWS = 3968;                  // one ragged cycle (4 images)

__device__ __forceinline__ unsigned short f2bf(float f) {
  unsigned int u = __float_as_uint(f);
  u += 0x7FFFu + ((u >> 16) & 1u);   // round-to-nearest-even
  return (unsigned short)(u >> 16);
}
__device__ __forceinline__ float bf2f(unsigned short u) {
  return __uint_as_float((unsigned int)u << 16);
}

// ---------------- pass 1: fp32 -> bf16 for A (seq_patches) and W ----------------
__global__ void cvt_kernel(const float* __restrict__ A, const float* __restrict__ W,
                           unsigned short* __restrict__ dst) {
  long chunk = (long)blockIdx.x * blockDim.x + threadIdx.x;  // one chunk = 8 floats
  long i = chunk * 8;
  const float* src = (i < A_ELEMS) ? (A + i) : (W + (i - A_ELEMS));
  float4 v0 = *(const float4*)(src);
  float4 v1 = *(const float4*)(src + 4);
  short8 o;
  o[0] = (short)f2bf(v0.x); o[1] = (short)f2bf(v0.y);
  o[2] = (short)f2bf(v0.z); o[3] = (short)f2bf(v0.w);
  o[4] = (short)f2bf(v1.x); o[5] = (short)f2bf(v1.y);
  o[6] = (short)f2bf(v1.z); o[7] = (short)f2bf(v1.w);
  *(short8*)(dst + i) = o;
}

// ---------------- pass 1b: pos table  tab[rem,d] = bf16(bias[d] + bilinear(pos)[rem,d]) ----
__global__ void tab_kernel(const float* __restrict__ pos, const float* __restrict__ bias,
                           unsigned short* __restrict__ tab) {
  const int t = blockIdx.x * blockDim.x + threadIdx.x;   // 571392 = 3968 * 144
  const int row = t / 144;                                // rem in [0,3968)
  const int dc = (t - row * 144) * 8;                     // d chunk base

  int rr, cc; float sy, sx;
  if (row < 1024)      { rr = row >> 5; cc = row & 31; sy = 0.5f;         sx = 0.5f; }
  else if (row < 2048) { const int li = row - 1024; rr = li >> 6; cc = li & 63; sy = 1.0f; sx = 0.25f; }
  else if (row < 3008) { const int li = row - 2048; rr = li / 40; cc = li - rr * 40; sy = 16.0f / 24.0f; sx = 0.4f; }
  else                 { const int li = row - 3008; rr = li / 24; cc = li - rr * 24; sy = 0.4f; sx = 16.0f / 24.0f; }
  float yc = fminf(fmaxf(((float)rr + 0.5f) * sy - 0.5f, 0.0f), 15.0f);
  const int y0 = (int)yc; const float fy = yc - (float)y0;
  const int y1 = y0 < 15 ? y0 + 1 : 15;
  float xc = fminf(fmaxf(((float)cc + 0.5f) * sx - 0.5f, 0.0f), 15.0f);
  const int x0 = (int)xc; const float fx = xc - (float)x0;
  const int x1 = x0 < 15 ? x0 + 1 : 15;
  const float w11 = fy * fx;
  const float w10 = fy - w11;
  const float w01 = fx - w11;
  const float w00 = 1.0f - fy - fx + w11;
  const float* p00 = pos + (size_t)(y0 * 16 + x0) * 1152 + dc;
  const float* p01 = pos + (size_t)(y0 * 16 + x1) * 1152 + dc;
  const float* p10 = pos + (size_t)(y1 * 16 + x0) * 1152 + dc;
  const float* p11 = pos + (size_t)(y1 * 16 + x1) * 1152 + dc;
  const float* bi  = bias + dc;
  short8 o;
#pragma unroll
  for (int j = 0; j < 8; ++j) {
    const float v = bi[j] + w00 * p00[j] + w01 * p01[j] + w10 * p10[j] + w11 * p11[j];
    o[j] = (short)f2bf(v);
  }
  *(short8*)(tab + (size_t)row * 1152 + dc) = o;
}

__device__ __forceinline__ void gload_lds16(const void* g, void* l) {
  __builtin_amdgcn_global_load_lds((__attribute__((address_space(1))) void*)g,
                                   (__attribute__((address_space(3))) void*)l, 16, 0, 0);
}

// ---------------- pass 2: 256x256 8-phase pipelined bf16 MFMA GEMM ----------------
// BM=BN=256, BK=64, 512 threads = 8 waves (2M x 4N), wave-tile 128x64.
// K-tile = 4 quarter-units of 16 KB: UA0/UA1 (A x k-half), UB0/UB1. LDS layout
// kk-major [buf][kk][256 rows][32 k] so units are LDS-contiguous (gload-able).
// 4 phases/K-tile: ph(kk, Msub) = {ds_read frags | stage 1 unit | bar | 16 MFMA | bar}.
// fb registers reused across the two Msub phases of each kk (halves B LDS reads).
// Stage slots (tile t): ph1->UA1(t+1), ph2->UB0(t+2), ph3->UA0(t+2), ph4->UB1(t+2).
// Every slot's LDS target was last ds_read one phase before re-stage (race-safe),
// and every vmcnt waits only on loads issued >=5 phases ago (~1200 cyc > 900 HBM):
// W2 = vmcnt(10) end-ph2, W1 = vmcnt(8) end-ph4 (tail: 8/4/0 by ledger).
__global__ __launch_bounds__(512, 2) void gemm_kernel(
    const unsigned short* __restrict__ Abf, const unsigned short* __restrict__ Wbf,
    const unsigned short* __restrict__ tab, float* __restrict__ outp) {
  __shared__ __attribute__((aligned(16))) unsigned short As[2 * 2 * 256 * 32];  // 64 KB
  __shared__ __attribute__((aligned(16))) unsigned short Bs[2 * 2 * 256 * 32];  // 64 KB

  // grid 620 = 124 m-tiles x 5 n-tiles; bijective XCD swizzle (q=77, r=4)
  const int bid = blockIdx.x;
  const int xcd = bid & 7, idx = bid >> 3;
  const int wgid = (xcd < 4 ? xcd * 78 : 312 + (xcd - 4) * 77) + idx;
  const int tm = wgid / 5, tn = wgid - tm * 5;
  const int m0 = tm * 256, n0 = tn * 256;   // tn==4: only cols 1024..1151 valid

  const int tid = threadIdx.x;
  const int w = tid >> 6, lane = tid & 63;
  const int wm = w >> 2, wn = w & 3;        // 2M x 4N waves, wave-tile 128x64
  const int kg = lane >> 4, l15 = lane & 15;
  const int rkey = (l15 >> 1) & 3;          // ds_read swizzle key (64-B rows, r7-proven)

  // staging: per unit a wave covers rows w*32..w*32+31 (2 gloads of 16 rows).
  // lane -> row lane>>2, chunk (lane&3), source chunk pre-swizzled by (lane>>3)&3.
  const int srow = lane >> 2;
  const int csrc = ((lane & 3) ^ ((lane >> 3) & 3)) * 8;   // element offset
  const int sdst = w * 2048;                // wave-uniform LDS byte base (g=0)

  const unsigned short* ApA = Abf + (size_t)(m0 + w * 32 + srow) * K_TOT + csrc;
  int brow0 = n0 + w * 32 + srow;      if (brow0 > N_TOT - 1) brow0 = N_TOT - 1;
  int brow1 = n0 + w * 32 + 16 + srow; if (brow1 > N_TOT - 1) brow1 = N_TOT - 1;
  const unsigned short* BpB0 = Wbf + (size_t)brow0 * K_TOT + csrc;
  const unsigned short* BpB1 = Wbf + (size_t)brow1 * K_TOT + csrc;

  f32x4 acc[8][4] = {};
  short8 fa[4], fb[4];

#define UOFF(p_, kk_) (((p_) * 2 + (kk_)) << 14)

#define STAGE_A(p_, kk_, kt_)                                                    \
  { const unsigned short* s_ = ApA + (kt_) * 64 + (kk_) * 32;                    \
    gload_lds16(s_, (char*)As + UOFF(p_, kk_) + sdst);                           \
    gload_lds16(s_ + (size_t)16 * K_TOT, (char*)As + UOFF(p_, kk_) + sdst + 1024); }

#define STAGE_B(p_, kk_, kt_)                                                    \
  { gload_lds16(BpB0 + (kt_) * 64 + (kk_) * 32, (char*)Bs + UOFF(p_, kk_) + sdst); \
    gload_lds16(BpB1 + (kt_) * 64 + (kk_) * 32, (char*)Bs + UOFF(p_, kk_) + sdst + 1024); }

#define LOAD_FA(p_, kk_, s_)                                                     \
  _Pragma("unroll") for (int j = 0; j < 4; ++j) {                                \
    const int ar_ = wm * 128 + (s_) * 64 + j * 16 + l15;                         \
    fa[j] = *(const short8*)((const char*)As + UOFF(p_, kk_) + ar_ * 64 +        \
                             ((kg ^ rkey) << 4));                                \
  }

#define LOAD_FB(p_, kk_)                                                         \
  _Pragma("unroll") for (int n = 0; n < 4; ++n) {                                \
    const int br_ = wn * 64 + n * 16 + l15;                                      \
    fb[n] = *(const short8*)((const char*)Bs + UOFF(p_, kk_) + br_ * 64 +        \
                             ((kg ^ rkey) << 4));                                \
  }

#define MFMA16(s_)                                                               \
  _Pragma("unroll") for (int j = 0; j < 4; ++j)                                  \
    _Pragma("unroll") for (int n = 0; n < 4; ++n)                                \
      acc[(s_) * 4 + j][n] = __builtin_amdgcn_mfma_f32_16x16x32_bf16(            \
          fa[j], fb[n], acc[(s_) * 4 + j][n], 0, 0, 0);

#define BAR __builtin_amdgcn_s_barrier()
#define SP1 __builtin_amdgcn_s_setprio(1)
#define SP0 __builtin_amdgcn_s_setprio(0)

  // prologue: issue 7 units in steady-state order, then retire the first 3.
  STAGE_B(0, 0, 0)   // UB0(T0)
  STAGE_A(0, 0, 0)   // UA0(T0)
  STAGE_B(0, 1, 0)   // UB1(T0)
  STAGE_A(0, 1, 0)   // UA1(T0)
  STAGE_B(1, 0, 1)   // UB0(T1)
  STAGE_A(1, 0, 1)   // UA0(T1)
  STAGE_B(1, 1, 1)   // UB1(T1)
  asm volatile("s_waitcnt vmcnt(8)" ::: "memory");   // UA0,UB0(T0) (+UB1(T0)) resident
  BAR;

#pragma unroll
  for (int t = 0; t < 12; ++t) {
    const int p = t & 1, q = p ^ 1;
    // ph1: kk0, Msub0.  stage UA1(t+1) -> buf q (As[q][kk1] last read t-1.ph4)
    LOAD_FB(p, 0)
    LOAD_FA(p, 0, 0)
    if (t + 1 <= 11) STAGE_A(q, 1, t + 1)
    BAR; SP1; MFMA16(0) SP0;
    BAR;
    // ph2: kk0, Msub1 (fb reused).  stage UB0(t+2) -> buf p (Bs[p][kk0] last read ph1)
    LOAD_FA(p, 0, 1)
    if (t + 2 <= 11) STAGE_B(p, 0, t + 2)
    BAR; SP1; MFMA16(1) SP0;
    if (t <= 9)       { asm volatile("s_waitcnt vmcnt(10)" ::: "memory"); }
    else if (t == 10) { asm volatile("s_waitcnt vmcnt(8)"  ::: "memory"); }
    else              { asm volatile("s_waitcnt vmcnt(0)"  ::: "memory"); }
    BAR;   // UA1,UB1(t) now resident for ph3
    // ph3: kk1, Msub0.  stage UA0(t+2) -> buf p (As[p][kk0] last read ph2)
    LOAD_FB(p, 1)
    LOAD_FA(p, 1, 0)
    if (t + 2 <= 11) STAGE_A(p, 0, t + 2)
    BAR; SP1; MFMA16(0) SP0;
    BAR;
    // ph4: kk1, Msub1.  stage UB1(t+2) -> buf p (Bs[p][kk1] last read ph3)
    LOAD_FA(p, 1, 1)
    if (t + 2 <= 11) STAGE_B(p, 1, t + 2)
    BAR; SP1; MFMA16(1) SP0;
    if (t <= 9)       { asm volatile("s_waitcnt vmcnt(8)" ::: "memory"); BAR; }
    else if (t == 10) { asm volatile("s_waitcnt vmcnt(4)" ::: "memory"); BAR; }
    // t==11: done, no wait/barrier
  }

#undef STAGE_A
#undef STAGE_B
#undef LOAD_FA
#undef LOAD_FB
#undef MFMA16
#undef UOFF

  // ---------------- epilogue: out = acc + tab[s % 3968, d] ----------------
  // acc[i][n]: row = m0 + wm*128 + (i>>2)*64 + (i&3)*16 + (lane>>4)*4 + r
  //            col = n0 + wn*64 + n*16 + l15
  const int d_base = n0 + wn * 64 + l15;
  if (d_base < N_TOT) {   // wave-uniform in effect (tn==4 -> wn>=2 skip)
    const int s_base = m0 + wm * 128 + ((lane >> 4) << 2);
    const int rem_b = s_base % CYC_ROWS;
#pragma unroll
    for (int i = 0; i < 8; ++i) {
      const int roff = ((i >> 2) << 6) + ((i & 3) << 4);
#pragma unroll
      for (int r = 0; r < 4; ++r) {
        int rem = rem_b + roff + r;
        if (rem >= CYC_ROWS) rem -= CYC_ROWS;
        const unsigned short* trow = tab + (size_t)rem * 1152 + d_base;
        float* orow = outp + (size_t)(s_base + roff + r) * 1152 + d_base;
#pragma unroll
        for (int n = 0; n < 4; ++n)
          orow[n * 16] = acc[i][n][r] + bf2f(trow[n * 16]);
      }
    }
  }
}

extern "C" void kernel_launch(void* const* d_in, const int* in_sizes, int n_in,
                              void* d_out, int out_size, void* d_ws, size_t ws_size,
                              hipStream_t stream) {
  const float* A    = (const float*)d_in[0];  // seq_patches [31744,768]
  const float* W    = (const float*)d_in[1];  // w [1152,768]
  const float* bias = (const float*)d_in[2];  // b [1152]
  const float* pos  = (const float*)d_in[3];  // pos_emb [256,1152]
  unsigned short* Abf = (unsigned short*)d_ws;            // 48.76 MB
  unsigned short* Wbf = Abf + A_ELEMS;                    // +1.77 MB
  unsigned short* tab = Wbf + W_ELEMS;                    // +9.14 MB (3968*1152)
  float* outp = (float*)d_out;

  cvt_kernel<<<12336, 256, 0, stream>>>(A, W, Abf);
  tab_kernel<<<2232, 256, 0, stream>>>(pos, bias, tab);
  gemm_kernel<<<620, 512, 0, stream>>>(Abf, Wbf, tab, outp);
}